// Round 7
// baseline (651.656 us; speedup 1.0000x reference)
//
#include <hip/hip_runtime.h>

// CharRNN fused: B=256, L=1024, V=40, H=128. One block/CU, 1024 thr = 16 waves
// = 4 waves/SIMD.
//
// R10: structural pivot -- j-parallel, LDS-broadcast h, in-wave reduce.
//   R9 post-mortem: chain-split and launch-bounds both neutral; VGPR_Count
//   pinned at 52 regardless of bounds. Model says ~450 cyc/step, measured
//   1290 -- the gap is common to every k-parallel variant: readlane blocks,
//   LDS partial exchange, and 2-waves/SIMD lockstep phasing. R10 removes all
//   three at once:
//   - wave w owns j-octet [8w,8w+8); lane (q=lane>>3, jj=lane&7) computes
//     j=8w+jj over k-slice [16q,16q+16). 24 persistent floats/lane.
//   - h_t in double-buffered LDS hbuf, bank-swizzled so each wave's 8
//     broadcast streams (8 lanes/addr) hit 8 distinct bank-quads.
//   - K-reduce: 3x __shfl_xor (8/16/32) + tanh, all in-wave. No partials
//     buffer. ONE barrier/step.
//   - logits: wave w covers all 40 v over k-slice [8w,8w+8) (h read as two
//     uniform float4 broadcasts); lpart window 8, burst every 8 steps.
//
// hbuf swizzle: 4-float block B stored at slot S(B)=B^((B>>3)&3) (bijective).
// Reader lane (q,i) wants block 4q+i -> slots spread over all 8 bank-quads
// for fixed i across q (verified: S&7 = 4(q&1) + (i^(q>>1)) hits 8 values).

#define BB 256
#define LL 1024
#define VV 40
#define HH 128
#define WIN 8
#define NW 16

__device__ __forceinline__ float fast_tanh(float x) {
    // tanh(x) = 1 - 2/(exp(2x)+1); overflow -> inf -> rcp -> 0 -> +1 (correct)
    float e = __expf(2.0f * x);
    float r = __builtin_amdgcn_rcpf(e + 1.0f);
    return 1.0f - 2.0f * r;
}

__device__ __forceinline__ int swz(int k) {
    // float index of h[k] inside a swizzled 128-float row
    int B = k >> 2;
    int S = B ^ ((B >> 3) & 3);
    return (S << 2) | (k & 3);
}

__global__ __launch_bounds__(1024) void rnn_fused(
    const int*   __restrict__ x,       // [B,L]
    const float* __restrict__ hidden,  // [B,H]
    const float* __restrict__ emb,     // [V,H]
    const float* __restrict__ Wh,      // [H,H]
    const float* __restrict__ Wo,      // [V,H]
    const float* __restrict__ b_h,     // [H]
    const float* __restrict__ b_y,     // [V]
    float*       __restrict__ out)     // [B*L*V logits][B*H final_hidden]
{
    __shared__ float emb_s[VV * HH];        // 20 KB (b_h folded in)
    __shared__ float hbuf[2][HH];           //  1 KB  dbuf hidden (swizzled)
    __shared__ float lpart[WIN][NW][48];    // 24 KB  logit partials (pad 40->48)
    __shared__ float bys[VV];
    __shared__ int   xbuf[LL];              //  4 KB
    // ~49.4 KB static LDS

    const int tid  = threadIdx.x;
    const int b    = blockIdx.x;
    const int w    = tid >> 6;          // wave 0..15
    const int lane = tid & 63;
    const int jj   = lane & 7;
    const int q    = lane >> 3;         // k-sixteenth selector
    const int j    = (w << 3) + jj;     // my output row

    // ---- stage x, embedding(+b_h), b_y, initial hidden (swizzled) ----
    {
        const int4* xg = (const int4*)(x + (size_t)b * LL);
        int4* xs = (int4*)xbuf;
        for (int i = tid; i < LL / 4; i += 1024) xs[i] = xg[i];
    }
    for (int i = tid; i < VV * HH; i += 1024)
        emb_s[i] = emb[i] + b_h[i & (HH - 1)];
    if (tid < VV) bys[tid] = b_y[tid];
    if (tid < HH) hbuf[0][swz(tid)] = hidden[(size_t)b * HH + tid];

    // ---- weights into registers (24 floats/lane) ----
    // whv[i] = Wh[j][16q+4i .. +3]; wo0/wo1 = Wo[min(lane,39)][8w .. 8w+8)
    float4 whv0, whv1, whv2, whv3, wo0, wo1;
    {
        const float4* p0 = (const float4*)(Wh + (size_t)j * HH + (q << 4));
        whv0 = p0[0]; whv1 = p0[1]; whv2 = p0[2]; whv3 = p0[3];
        int vrow = (lane < VV) ? lane : 0;
        const float4* p2 = (const float4*)(Wo + (size_t)vrow * HH + (w << 3));
        wo0 = p2[0]; wo1 = p2[1];
    }

    // per-lane constant float4-slot indices into the swizzled h row
    const int B0 = (q << 2), B1 = B0 + 1, B2 = B0 + 2, B3 = B0 + 3;
    const int s0 = B0 ^ ((B0 >> 3) & 3);
    const int s1 = B1 ^ ((B1 >> 3) & 3);
    const int s2 = B2 ^ ((B2 >> 3) & 3);
    const int s3 = B3 ^ ((B3 >> 3) & 3);
    const int Bb0 = (w << 1), Bb1 = Bb0 + 1;
    const int sb0 = Bb0 ^ ((Bb0 >> 3) & 3);
    const int sb1 = Bb1 ^ ((Bb1 >> 3) & 3);

    __syncthreads();

    int p = 0;
    int idx_cur = xbuf[0];
    float hlast = 0.f;

    for (int t = 0; t < LL; ++t) {
        const float4* hp = (const float4*)hbuf[p];
        // main-dot h: 4 x b128, 8 distinct addrs/wave (8-lane broadcast),
        // swizzle spreads them over 8 bank-quads -> conflict-free
        float4 hv0 = hp[s0], hv1 = hp[s1], hv2 = hp[s2], hv3 = hp[s3];
        // logit h: 2 x b128 uniform broadcast
        float4 hb0 = hp[sb0], hb1 = hp[sb1];
        float e_cur = emb_s[idx_cur * HH + j];    // 8 lanes/addr broadcast
        int tn = t + 1; if (tn > LL - 1) tn = LL - 1;
        int idx_next = xbuf[tn];

        // ---- main dot: my j, my k-sixteenth (16 FMA, 4 chains) ----
        float a0 = fmaf(hv1.x, whv1.x, hv0.x * whv0.x);
        float a1 = fmaf(hv1.y, whv1.y, hv0.y * whv0.y);
        float a2 = fmaf(hv1.z, whv1.z, hv0.z * whv0.z);
        float a3 = fmaf(hv1.w, whv1.w, hv0.w * whv0.w);
        a0 = fmaf(hv2.x, whv2.x, a0); a1 = fmaf(hv2.y, whv2.y, a1);
        a2 = fmaf(hv2.z, whv2.z, a2); a3 = fmaf(hv2.w, whv2.w, a3);
        a0 = fmaf(hv3.x, whv3.x, a0); a1 = fmaf(hv3.y, whv3.y, a1);
        a2 = fmaf(hv3.z, whv3.z, a2); a3 = fmaf(hv3.w, whv3.w, a3);
        float acc = (a0 + a1) + (a2 + a3);

        // ---- logit partial: v = lane(<40), k in [8w, 8w+8) (8 FMA) ----
        float l0 = fmaf(hb1.x, wo1.x, hb0.x * wo0.x);
        float l1 = fmaf(hb1.y, wo1.y, hb0.y * wo0.y);
        float l2 = fmaf(hb1.z, wo1.z, hb0.z * wo0.z);
        float l3 = fmaf(hb1.w, wo1.w, hb0.w * wo0.w);
        float lacc = (l0 + l1) + (l2 + l3);

        // ---- in-wave K-reduce over q (lanes xor 8/16/32) + tanh ----
        acc += __shfl_xor(acc, 8);
        acc += __shfl_xor(acc, 16);
        acc += __shfl_xor(acc, 32);
        float hval = fast_tanh(acc + e_cur);
        hlast = hval;

        if (q == 0) hbuf[p ^ 1][swz(j)] = hval;
        if (t != 0 && lane < VV) lpart[(t - 1) & (WIN - 1)][w][lane] = lacc;
        __syncthreads();

        // ---- burst: reduce+store logit rows [t-8, t) ----
        if (t >= WIN && (t & (WIN - 1)) == 0) {
            if (tid < WIN * VV) {               // 320 threads
                int tp = tid / VV;
                int v  = tid - VV * tp;
                float sm = bys[v];
                #pragma unroll
                for (int g = 0; g < NW; ++g) sm += lpart[tp][g][v];
                out[(size_t)b * LL * VV + (size_t)(t - WIN + tp) * VV + v] = sm;
            }
            __syncthreads();   // next step's lpart[0] write must wait
        }

        idx_cur = idx_next;
        p ^= 1;
    }

    // ---- epilogue: logits for row L-1 from final h, then last burst ----
    {
        const float4* hp = (const float4*)hbuf[p];   // final h (post-toggle)
        float4 hb0 = hp[sb0], hb1 = hp[sb1];
        float l0 = fmaf(hb1.x, wo1.x, hb0.x * wo0.x);
        float l1 = fmaf(hb1.y, wo1.y, hb0.y * wo0.y);
        float l2 = fmaf(hb1.z, wo1.z, hb0.z * wo0.z);
        float l3 = fmaf(hb1.w, wo1.w, hb0.w * wo0.w);
        float lacc = (l0 + l1) + (l2 + l3);
        if (lane < VV) lpart[(LL - 1) & (WIN - 1)][w][lane] = lacc;
        __syncthreads();
        const int rbase = LL - WIN;
        if (tid < WIN * VV) {
            int tp = tid / VV;
            int v  = tid - VV * tp;
            float sm = bys[v];
            #pragma unroll
            for (int g = 0; g < NW; ++g) sm += lpart[tp][g][v];
            out[(size_t)b * LL * VV + (size_t)(rbase + tp) * VV + v] = sm;
        }
        // final hidden
        if (q == 0)
            out[(size_t)BB * LL * VV + (size_t)b * HH + j] = hlast;
    }
}

extern "C" void kernel_launch(void* const* d_in, const int* in_sizes, int n_in,
                              void* d_out, int out_size, void* d_ws, size_t ws_size,
                              hipStream_t stream) {
    const int*   x      = (const int*)  d_in[0];
    const float* hidden = (const float*)d_in[1];
    const float* emb    = (const float*)d_in[2];
    const float* Wh     = (const float*)d_in[3];
    const float* Wo     = (const float*)d_in[4];
    const float* bh     = (const float*)d_in[5];
    const float* by     = (const float*)d_in[6];
    float*       out    = (float*)      d_out;

    rnn_fused<<<dim3(BB), dim3(1024), 0, stream>>>(x, hidden, emb, Wh, Wo, bh, by, out);
}

// Round 11
// 643.051 us; speedup vs baseline: 1.0134x; 1.0134x over previous
//
#include <hip/hip_runtime.h>

// CharRNN fused, MFMA v4: TWO-PHASE.  B=256, L=1024, V=40, H=128.
//
// R11-R13 all NaN'd in the LOGIT MFMA cluster while R13's detectors proved
// the B-fragments (LDS h) and the main Wh-MFMA outputs clean through all
// 1024 steps (absmax sentinel = 1e30 band, bad_b=bad_c=0). Bounded operands
// cannot produce NaN => the in-loop logit cluster's registers (woA/pInit,
// the only undetected operands) get corrupted -- regalloc/codegen pathology
// around the second, divergently-guarded MFMA cluster. R14 amputates it:
//
// Phase 1 rnn_recur (16 blocks x 256): recurrence ONLY (the verified-clean
//   machinery), streaming h_t as bf16 to d_ws workspace H[B][L][128] (64 MB).
//   Detectors kept: bad_b (LDS h garbage) -> 5e30, bad_c (main MFMA garbage)
//   -> 3e30, encoded in the final-hidden output (Output 1).
// Phase 2 logits_gemm (1024 blocks x 256): out[r][v] = H[r]. Wo^T + b_y for
//   r = b*L+t (uniform, covers ALL rows incl. L-1 -- no epilogue). 3 Wo
//   v-tiles (zero-padded past 40), B-frags straight from global, no LDS.
//   Stores qnan-clamped so any H garbage shows as 1e30, not NaN.
// Same stream => phase 2 starts after phase 1 completes.
//
// MFMA 16x16x32 bf16 maps (m89-verified D; A/B share one k-map so any
// k-permutation cancels): lane l = (q=l>>4, n=l&15):
//   A: row = n, k = q*8+e  |  B: col = n, k = q*8+e  |  D: col = n, row = 4q+r

#define BB 256
#define LL 1024
#define VV 40
#define HH 128
#define MB 16           // batch per block (phase 1)
#define EP 132          // LDS row pitch (floats)

typedef __bf16 bf16x8 __attribute__((ext_vector_type(8)));
typedef __bf16 bf16x4 __attribute__((ext_vector_type(4)));
typedef float  f32x4  __attribute__((ext_vector_type(4)));

#define MFMA(a, b, c) __builtin_amdgcn_mfma_f32_16x16x32_bf16((a), (b), (c), 0, 0, 0)

__device__ __forceinline__ float fast_tanh(float x) {
    // tanh(x) = 1 - 2/(exp(2x)+1); overflow -> inf -> rcp -> 0 -> +1 (correct)
    float e = __expf(2.0f * x);
    float r = __builtin_amdgcn_rcpf(e + 1.0f);
    return 1.0f - 2.0f * r;
}

__device__ __forceinline__ float clamp1(float x) {   // NaN -> -1, else clamp
    return fminf(1.0f, fmaxf(-1.0f, x));
}
__device__ __forceinline__ float qnan(float x) {     // NaN/huge -> +-1e30
    return fminf(1.0e30f, fmaxf(-1.0e30f, x));
}

// ============================ PHASE 1 ====================================
__global__ __launch_bounds__(256) void rnn_recur(
    const int*   __restrict__ x,       // [B,L]
    const float* __restrict__ hidden,  // [B,H]
    const float* __restrict__ emb,     // [V,H]
    const float* __restrict__ Wh,      // [H,H]
    const float* __restrict__ b_h,     // [H]
    float*       __restrict__ out,     // final hidden -> out[B*L*V ..]
    __bf16*      __restrict__ Hws)     // [B,L,H] bf16 workspace
{
    __shared__ float emb_s[VV * EP];                   // 20.6 KB, b_h folded
    __shared__ __align__(16) float h_s[2][MB][EP];     // 16.9 KB, fp32, linear

    const int tid  = threadIdx.x;
    const int w    = tid >> 6;          // wave 0..3
    const int lane = tid & 63;
    const int m    = lane & 15;         // batch column (B col, D col)
    const int q    = lane >> 4;         // 0..3
    const int b0   = blockIdx.x * MB;

    for (int i = tid; i < VV * HH; i += 256) {
        int v = i >> 7, j = i & (HH - 1);
        emb_s[v * EP + j] = emb[i] + b_h[j];
    }
    for (int i = tid; i < MB * HH; i += 256) {
        int mm = i >> 7, j = i & (HH - 1);
        h_s[0][mm][j] = hidden[(size_t)(b0 + mm) * HH + j];
    }

    // static A-fragments: Wh, 2 M-tiles/wave (rows j=(2w+i)*16+m)
    bf16x8 whA[2][4];
    #pragma unroll
    for (int i = 0; i < 2; ++i) {
        int j = (2 * w + i) * 16 + m;
        #pragma unroll
        for (int kt = 0; kt < 4; ++kt) {
            const float* pw = Wh + (size_t)j * HH + kt * 32 + q * 8;
            bf16x8 f;
            #pragma unroll
            for (int e = 0; e < 8; ++e) f[e] = (__bf16)pw[e];
            whA[i][kt] = f;
        }
    }

    const int* xrow = x + (size_t)(b0 + m) * LL;
    const int j00 = 32 * w + 4 * q;          // D row-quad base, M-tile 0
    const int j01 = j00 + 16;                // D row-quad base, M-tile 1
    int xl_nxt = xrow[1];
    __syncthreads();

    f32x4 e0, e1;
    {
        int idx0 = xrow[0];
        e0 = *(const f32x4*)&emb_s[idx0 * EP + j00];
        e1 = *(const f32x4*)&emb_s[idx0 * EP + j01];
    }

    const size_t hrow_base = (size_t)(b0 + m) * LL;   // H row index base
    int p = 0;
    int bad_b = 0, bad_c = 0;

    for (int t = 0; t < LL; ++t) {
        // ---- B-path: 8x f32x4 linear LDS reads, k-map = A's ----
        const float* hrow = h_s[p][m];
        f32x4 r0 = *(const f32x4*)&hrow[      q * 8];
        f32x4 r1 = *(const f32x4*)&hrow[      q * 8 + 4];
        f32x4 r2 = *(const f32x4*)&hrow[32 +  q * 8];
        f32x4 r3 = *(const f32x4*)&hrow[32 +  q * 8 + 4];
        f32x4 r4 = *(const f32x4*)&hrow[64 +  q * 8];
        f32x4 r5 = *(const f32x4*)&hrow[64 +  q * 8 + 4];
        f32x4 r6 = *(const f32x4*)&hrow[96 +  q * 8];
        f32x4 r7 = *(const f32x4*)&hrow[96 +  q * 8 + 4];

        // ---- B-garbage detector (|h|<=1 by construction; NaN self-cmp) ----
        {
            float mx = 0.f;
            f32x4 sa = r0 + r1 + r2 + r3 + r4 + r5 + r6 + r7;
            #pragma unroll
            for (int r = 0; r < 4; ++r) {
                mx = fmaxf(mx, fabsf(r0[r])); mx = fmaxf(mx, fabsf(r1[r]));
                mx = fmaxf(mx, fabsf(r2[r])); mx = fmaxf(mx, fabsf(r3[r]));
                mx = fmaxf(mx, fabsf(r4[r])); mx = fmaxf(mx, fabsf(r5[r]));
                mx = fmaxf(mx, fabsf(r6[r])); mx = fmaxf(mx, fabsf(r7[r]));
            }
            float s = (sa[0] + sa[1]) + (sa[2] + sa[3]);
            bad_b |= (mx > 1.01f) | (s != s) | (fabsf(s) > 1.0e4f);
        }

        // ---- B-fragments (plain casts) ----
        bf16x8 B0, B1, B2, B3;
        #pragma unroll
        for (int r = 0; r < 4; ++r) {
            B0[r] = (__bf16)r0[r]; B0[r + 4] = (__bf16)r1[r];
            B1[r] = (__bf16)r2[r]; B1[r + 4] = (__bf16)r3[r];
            B2[r] = (__bf16)r4[r]; B2[r + 4] = (__bf16)r5[r];
            B3[r] = (__bf16)r6[r]; B3[r + 4] = (__bf16)r7[r];
        }

        int tn  = (t + 2 < LL) ? t + 2 : LL - 1;
        int xl2 = xrow[tn];

        // ---- main MFMAs: pre-activation, C initialized with e_t ----
        f32x4 c0 = e0, c1 = e1;
        c0 = MFMA(whA[0][0], B0, c0); c0 = MFMA(whA[0][1], B1, c0);
        c0 = MFMA(whA[0][2], B2, c0); c0 = MFMA(whA[0][3], B3, c0);
        c1 = MFMA(whA[1][0], B0, c1); c1 = MFMA(whA[1][1], B1, c1);
        c1 = MFMA(whA[1][2], B2, c1); c1 = MFMA(whA[1][3], B3, c1);

        // ---- c-garbage detector (legit |c| <= ~13) ----
        {
            float cm = 0.f, cs = 0.f;
            #pragma unroll
            for (int r = 0; r < 4; ++r) {
                cm = fmaxf(cm, fabsf(c0[r])); cm = fmaxf(cm, fabsf(c1[r]));
                cs += c0[r] + c1[r];
            }
            bad_c |= (cm > 100.f) | (cs != cs);
        }

        // ---- e for t+1 ----
        e0 = *(const f32x4*)&emb_s[xl_nxt * EP + j00];
        e1 = *(const f32x4*)&emb_s[xl_nxt * EP + j01];
        xl_nxt = xl2;

        // ---- tanh + clamp, write h_t to LDS and to H workspace (bf16) ----
        f32x4 h0, h1;
        #pragma unroll
        for (int r = 0; r < 4; ++r) {
            h0[r] = clamp1(fast_tanh(c0[r]));
            h1[r] = clamp1(fast_tanh(c1[r]));
        }
        *(f32x4*)&h_s[p ^ 1][m][j00] = h0;
        *(f32x4*)&h_s[p ^ 1][m][j01] = h1;

        bf16x4 g0, g1;
        #pragma unroll
        for (int r = 0; r < 4; ++r) { g0[r] = (__bf16)h0[r]; g1[r] = (__bf16)h1[r]; }
        __bf16* hw = Hws + ((hrow_base + t) << 7);    // *HH
        *(bf16x4*)&hw[j00] = g0;
        *(bf16x4*)&hw[j01] = g1;

        if (t == LL - 1) {   // final hidden (Output 1) carries the sentinels
            float* fh = out + (size_t)BB * LL * VV + (size_t)(b0 + m) * HH;
            float s0[4], s1[4];
            #pragma unroll
            for (int r = 0; r < 4; ++r) {
                s0[r] = bad_b ? 5.0e30f : (bad_c ? 3.0e30f : h0[r]);
                s1[r] = bad_b ? 5.0e30f : (bad_c ? 3.0e30f : h1[r]);
            }
            *(float4*)(fh + j00) = make_float4(s0[0], s0[1], s0[2], s0[3]);
            *(float4*)(fh + j01) = make_float4(s1[0], s1[1], s1[2], s1[3]);
        }

        __syncthreads();
        p ^= 1;
    }
}

// ============================ PHASE 2 ====================================
// out[r][v] = sum_k H[r][k] * Wo[v][k] + b_y[v],  r = b*L+t in [0, B*L).
// Block: 256 rows (4 waves x 64). Wave: 4 groups of 16 rows.
// D[v x row16]: A = Wo (3 v-tiles, zero-padded), B = H^T (frags from global).
__global__ __launch_bounds__(256) void logits_gemm(
    const __bf16* __restrict__ Hws,    // [B*L, H] bf16
    const float*  __restrict__ Wo,     // [V,H]
    const float*  __restrict__ b_y,    // [V]
    float*        __restrict__ out)    // [B*L, V]
{
    const int tid  = threadIdx.x;
    const int w    = tid >> 6;
    const int lane = tid & 63;
    const int n    = lane & 15;         // col within 16-row group
    const int q    = lane >> 4;
    const int rbase = blockIdx.x * 256 + w * 64;

    // A-fragments: Wo v-tiles (rows v = vt*16+n; zero past VV)
    bf16x8 woA[3][4];
    f32x4  pInit[3];
    #pragma unroll
    for (int vt = 0; vt < 3; ++vt) {
        int vrow = vt * 16 + n;
        #pragma unroll
        for (int kt = 0; kt < 4; ++kt) {
            bf16x8 f;
            #pragma unroll
            for (int e = 0; e < 8; ++e) {
                float fv = 0.f;
                if (vrow < VV) fv = Wo[(size_t)vrow * HH + kt * 32 + q * 8 + e];
                f[e] = (__bf16)fv;
            }
            woA[vt][kt] = f;
        }
        #pragma unroll
        for (int r = 0; r < 4; ++r) {
            int v = vt * 16 + 4 * q + r;
            pInit[vt][r] = (v < VV) ? b_y[v] : 0.f;
        }
    }

    #pragma unroll
    for (int g = 0; g < 4; ++g) {
        const size_t row = (size_t)rbase + g * 16 + n;
        const __bf16* rp = Hws + (row << 7);          // *HH
        bf16x8 B0 = *(const bf16x8*)&rp[ 0 + q * 8];
        bf16x8 B1 = *(const bf16x8*)&rp[32 + q * 8];
        bf16x8 B2 = *(const bf16x8*)&rp[64 + q * 8];
        bf16x8 B3 = *(const bf16x8*)&rp[96 + q * 8];

        f32x4 p0 = pInit[0], p1 = pInit[1], p2 = pInit[2];
        p0 = MFMA(woA[0][0], B0, p0); p0 = MFMA(woA[0][1], B1, p0);
        p0 = MFMA(woA[0][2], B2, p0); p0 = MFMA(woA[0][3], B3, p0);
        p1 = MFMA(woA[1][0], B0, p1); p1 = MFMA(woA[1][1], B1, p1);
        p1 = MFMA(woA[1][2], B2, p1); p1 = MFMA(woA[1][3], B3, p1);
        p2 = MFMA(woA[2][0], B0, p2); p2 = MFMA(woA[2][1], B1, p2);
        p2 = MFMA(woA[2][2], B2, p2); p2 = MFMA(woA[2][3], B3, p2);

        // stores: lane holds D[v = vt*16+4q+r][row]; v-quads contiguous
        float* orow = out + row * VV;
        *(float4*)(orow + 4 * q) =
            make_float4(qnan(p0[0]), qnan(p0[1]), qnan(p0[2]), qnan(p0[3]));
        *(float4*)(orow + 16 + 4 * q) =
            make_float4(qnan(p1[0]), qnan(p1[1]), qnan(p1[2]), qnan(p1[3]));
        if (q < 2)
            *(float4*)(orow + 32 + 4 * q) =
                make_float4(qnan(p2[0]), qnan(p2[1]), qnan(p2[2]), qnan(p2[3]));
    }
}

extern "C" void kernel_launch(void* const* d_in, const int* in_sizes, int n_in,
                              void* d_out, int out_size, void* d_ws, size_t ws_size,
                              hipStream_t stream) {
    const int*   x      = (const int*)  d_in[0];
    const float* hidden = (const float*)d_in[1];
    const float* emb    = (const float*)d_in[2];
    const float* Wh     = (const float*)d_in[3];
    const float* Wo     = (const float*)d_in[4];
    const float* bh     = (const float*)d_in[5];
    const float* by     = (const float*)d_in[6];
    float*       out    = (float*)      d_out;
    __bf16*      Hws    = (__bf16*)     d_ws;   // needs B*L*H*2 = 64 MB

    rnn_recur<<<dim3(BB / MB), dim3(256), 0, stream>>>(x, hidden, emb, Wh, bh, out, Hws);
    logits_gemm<<<dim3(BB * LL / 256), dim3(256), 0, stream>>>(Hws, Wo, by, out);
}

// Round 12
// 557.405 us; speedup vs baseline: 1.1691x; 1.1537x over previous
//
#include <hip/hip_runtime.h>

// CharRNN fused, MFMA v5: TWO-PHASE, lean recurrence.  B=256, L=1024, V=40, H=128.
//
// R14 passed (absmax 3.9e-3): phase-1 recurrence + phase-2 logits GEMM, after
// R11-R13 isolated a corruption specific to an in-loop guarded logit-MFMA
// cluster (amputated). R14 counters: rnn_recur 544us = 1275 cyc/step at 16
// blocks; chain model says ~550. Culprit: __syncthreads() emits
// s_waitcnt vmcnt(0) before s_barrier, so the per-step x global load and the
// 2 Hws global stores are forced to COMPLETION inside the serial recurrence
// (~200-900 cyc each). R15:
//   1. Raw barrier in-loop: s_waitcnt lgkmcnt(0) + s_barrier (+sched_barrier,
//      guide rule #18). LDS h-writes are lgkmcnt-tracked -> dbuf still
//      race-free; Hws stores / x-load drain lazily (compiler inserts counted
//      vmcnt before xl_nxt's USE, a full iteration of slack).
//   2. Detectors stripped (R13/R14 did their job); clamp1 kept (NaN-safe
//      recurrence), phase-2 qnan bands kept (failures stay finite+decodable).
//
// MFMA 16x16x32 bf16 maps (m89-verified D; A/B share one k-map so any
// k-permutation cancels): lane l = (q=l>>4, n=l&15):
//   A: row = n, k = q*8+e  |  B: col = n, k = q*8+e  |  D: col = n, row = 4q+r

#define BB 256
#define LL 1024
#define VV 40
#define HH 128
#define MB 16           // batch per block (phase 1)
#define EP 132          // LDS row pitch (floats)

typedef __bf16 bf16x8 __attribute__((ext_vector_type(8)));
typedef __bf16 bf16x4 __attribute__((ext_vector_type(4)));
typedef float  f32x4  __attribute__((ext_vector_type(4)));

#define MFMA(a, b, c) __builtin_amdgcn_mfma_f32_16x16x32_bf16((a), (b), (c), 0, 0, 0)

__device__ __forceinline__ float fast_tanh(float x) {
    // tanh(x) = 1 - 2/(exp(2x)+1); overflow -> inf -> rcp -> 0 -> +1 (correct)
    float e = __expf(2.0f * x);
    float r = __builtin_amdgcn_rcpf(e + 1.0f);
    return 1.0f - 2.0f * r;
}

__device__ __forceinline__ float clamp1(float x) {   // NaN -> -1, else clamp
    return fminf(1.0f, fmaxf(-1.0f, x));
}
__device__ __forceinline__ float qnan(float x) {     // NaN/huge -> +-1e30
    return fminf(1.0e30f, fmaxf(-1.0e30f, x));
}

// ============================ PHASE 1 ====================================
__global__ __launch_bounds__(256) void rnn_recur(
    const int*   __restrict__ x,       // [B,L]
    const float* __restrict__ hidden,  // [B,H]
    const float* __restrict__ emb,     // [V,H]
    const float* __restrict__ Wh,      // [H,H]
    const float* __restrict__ b_h,     // [H]
    float*       __restrict__ out,     // final hidden -> out[B*L*V ..]
    __bf16*      __restrict__ Hws)     // [B,L,H] bf16 workspace
{
    __shared__ float emb_s[VV * EP];                   // 20.6 KB, b_h folded
    __shared__ __align__(16) float h_s[2][MB][EP];     // 16.9 KB, fp32, linear

    const int tid  = threadIdx.x;
    const int w    = tid >> 6;          // wave 0..3
    const int lane = tid & 63;
    const int m    = lane & 15;         // batch column (B col, D col)
    const int q    = lane >> 4;         // 0..3
    const int b0   = blockIdx.x * MB;

    for (int i = tid; i < VV * HH; i += 256) {
        int v = i >> 7, j = i & (HH - 1);
        emb_s[v * EP + j] = emb[i] + b_h[j];
    }
    for (int i = tid; i < MB * HH; i += 256) {
        int mm = i >> 7, j = i & (HH - 1);
        h_s[0][mm][j] = hidden[(size_t)(b0 + mm) * HH + j];
    }

    // static A-fragments: Wh, 2 M-tiles/wave (rows j=(2w+i)*16+m)
    bf16x8 whA[2][4];
    #pragma unroll
    for (int i = 0; i < 2; ++i) {
        int j = (2 * w + i) * 16 + m;
        #pragma unroll
        for (int kt = 0; kt < 4; ++kt) {
            const float* pw = Wh + (size_t)j * HH + kt * 32 + q * 8;
            bf16x8 f;
            #pragma unroll
            for (int e = 0; e < 8; ++e) f[e] = (__bf16)pw[e];
            whA[i][kt] = f;
        }
    }

    const int* xrow = x + (size_t)(b0 + m) * LL;
    const int j00 = 32 * w + 4 * q;          // D row-quad base, M-tile 0
    const int j01 = j00 + 16;                // D row-quad base, M-tile 1
    int xl_nxt = xrow[1];
    __syncthreads();                         // staging complete (full barrier ok)

    f32x4 e0, e1;
    {
        int idx0 = xrow[0];
        e0 = *(const f32x4*)&emb_s[idx0 * EP + j00];
        e1 = *(const f32x4*)&emb_s[idx0 * EP + j01];
    }

    const size_t hrow_base = (size_t)(b0 + m) * LL;   // H row index base
    int p = 0;

    for (int t = 0; t < LL; ++t) {
        // ---- B-path: 8x f32x4 linear LDS reads, k-map = A's ----
        const float* hrow = h_s[p][m];
        f32x4 r0 = *(const f32x4*)&hrow[      q * 8];
        f32x4 r1 = *(const f32x4*)&hrow[      q * 8 + 4];
        f32x4 r2 = *(const f32x4*)&hrow[32 +  q * 8];
        f32x4 r3 = *(const f32x4*)&hrow[32 +  q * 8 + 4];
        f32x4 r4 = *(const f32x4*)&hrow[64 +  q * 8];
        f32x4 r5 = *(const f32x4*)&hrow[64 +  q * 8 + 4];
        f32x4 r6 = *(const f32x4*)&hrow[96 +  q * 8];
        f32x4 r7 = *(const f32x4*)&hrow[96 +  q * 8 + 4];

        // ---- B-fragments (plain casts) ----
        bf16x8 B0, B1, B2, B3;
        #pragma unroll
        for (int r = 0; r < 4; ++r) {
            B0[r] = (__bf16)r0[r]; B0[r + 4] = (__bf16)r1[r];
            B1[r] = (__bf16)r2[r]; B1[r + 4] = (__bf16)r3[r];
            B2[r] = (__bf16)r4[r]; B2[r + 4] = (__bf16)r5[r];
            B3[r] = (__bf16)r6[r]; B3[r + 4] = (__bf16)r7[r];
        }

        int tn  = (t + 2 < LL) ? t + 2 : LL - 1;
        int xl2 = xrow[tn];                  // global; drains lazily (raw barrier)

        // ---- main MFMAs: pre-activation, C initialized with e_t ----
        f32x4 c0 = e0, c1 = e1;
        c0 = MFMA(whA[0][0], B0, c0); c0 = MFMA(whA[0][1], B1, c0);
        c0 = MFMA(whA[0][2], B2, c0); c0 = MFMA(whA[0][3], B3, c0);
        c1 = MFMA(whA[1][0], B0, c1); c1 = MFMA(whA[1][1], B1, c1);
        c1 = MFMA(whA[1][2], B2, c1); c1 = MFMA(whA[1][3], B3, c1);

        // ---- e for t+1 (emb_s read-only; xl_nxt from last iter's load) ----
        e0 = *(const f32x4*)&emb_s[xl_nxt * EP + j00];
        e1 = *(const f32x4*)&emb_s[xl_nxt * EP + j01];
        xl_nxt = xl2;

        // ---- tanh + clamp, write h_t to LDS dbuf and H workspace (bf16) ----
        f32x4 h0, h1;
        #pragma unroll
        for (int r = 0; r < 4; ++r) {
            h0[r] = clamp1(fast_tanh(c0[r]));
            h1[r] = clamp1(fast_tanh(c1[r]));
        }
        *(f32x4*)&h_s[p ^ 1][m][j00] = h0;
        *(f32x4*)&h_s[p ^ 1][m][j01] = h1;

        bf16x4 g0, g1;
        #pragma unroll
        for (int r = 0; r < 4; ++r) { g0[r] = (__bf16)h0[r]; g1[r] = (__bf16)h1[r]; }
        __bf16* hw = Hws + ((hrow_base + t) << 7);    // *HH
        *(bf16x4*)&hw[j00] = g0;                      // stores stay in flight
        *(bf16x4*)&hw[j01] = g1;

        if (t == LL - 1) {                   // final hidden (Output 1)
            float* fh = out + (size_t)BB * LL * VV + (size_t)(b0 + m) * HH;
            *(float4*)(fh + j00) = make_float4(h0[0], h0[1], h0[2], h0[3]);
            *(float4*)(fh + j01) = make_float4(h1[0], h1[1], h1[2], h1[3]);
        }

        // ---- RAW barrier: LDS-only drain; global stores/load NOT drained.
        // ds_write retirement is lgkmcnt-tracked -> dbuf handoff is race-free.
        asm volatile("s_waitcnt lgkmcnt(0)" ::: "memory");
        __builtin_amdgcn_s_barrier();
        __builtin_amdgcn_sched_barrier(0);   // rule #18: pin code after wait
        p ^= 1;
    }
}

// ============================ PHASE 2 ====================================
// out[r][v] = sum_k H[r][k] * Wo[v][k] + b_y[v],  r = b*L+t in [0, B*L).
// Block: 256 rows (4 waves x 64). Wave: 4 groups of 16 rows.
// D[v x row16]: A = Wo (3 v-tiles, zero-padded), B = H^T (frags from global).
__global__ __launch_bounds__(256) void logits_gemm(
    const __bf16* __restrict__ Hws,    // [B*L, H] bf16
    const float*  __restrict__ Wo,     // [V,H]
    const float*  __restrict__ b_y,    // [V]
    float*        __restrict__ out)    // [B*L, V]
{
    const int tid  = threadIdx.x;
    const int w    = tid >> 6;
    const int lane = tid & 63;
    const int n    = lane & 15;         // col within 16-row group
    const int q    = lane >> 4;
    const int rbase = blockIdx.x * 256 + w * 64;

    // A-fragments: Wo v-tiles (rows v = vt*16+n; zero past VV)
    bf16x8 woA[3][4];
    f32x4  pInit[3];
    #pragma unroll
    for (int vt = 0; vt < 3; ++vt) {
        int vrow = vt * 16 + n;
        #pragma unroll
        for (int kt = 0; kt < 4; ++kt) {
            bf16x8 f;
            #pragma unroll
            for (int e = 0; e < 8; ++e) {
                float fv = 0.f;
                if (vrow < VV) fv = Wo[(size_t)vrow * HH + kt * 32 + q * 8 + e];
                f[e] = (__bf16)fv;
            }
            woA[vt][kt] = f;
        }
        #pragma unroll
        for (int r = 0; r < 4; ++r) {
            int v = vt * 16 + 4 * q + r;
            pInit[vt][r] = (v < VV) ? b_y[v] : 0.f;
        }
    }

    #pragma unroll
    for (int g = 0; g < 4; ++g) {
        const size_t row = (size_t)rbase + g * 16 + n;
        const __bf16* rp = Hws + (row << 7);          // *HH
        bf16x8 B0 = *(const bf16x8*)&rp[ 0 + q * 8];
        bf16x8 B1 = *(const bf16x8*)&rp[32 + q * 8];
        bf16x8 B2 = *(const bf16x8*)&rp[64 + q * 8];
        bf16x8 B3 = *(const bf16x8*)&rp[96 + q * 8];

        f32x4 p0 = pInit[0], p1 = pInit[1], p2 = pInit[2];
        p0 = MFMA(woA[0][0], B0, p0); p0 = MFMA(woA[0][1], B1, p0);
        p0 = MFMA(woA[0][2], B2, p0); p0 = MFMA(woA[0][3], B3, p0);
        p1 = MFMA(woA[1][0], B0, p1); p1 = MFMA(woA[1][1], B1, p1);
        p1 = MFMA(woA[1][2], B2, p1); p1 = MFMA(woA[1][3], B3, p1);
        p2 = MFMA(woA[2][0], B0, p2); p2 = MFMA(woA[2][1], B1, p2);
        p2 = MFMA(woA[2][2], B2, p2); p2 = MFMA(woA[2][3], B3, p2);

        // stores: lane holds D[v = vt*16+4q+r][row]; v-quads contiguous
        float* orow = out + row * VV;
        *(float4*)(orow + 4 * q) =
            make_float4(qnan(p0[0]), qnan(p0[1]), qnan(p0[2]), qnan(p0[3]));
        *(float4*)(orow + 16 + 4 * q) =
            make_float4(qnan(p1[0]), qnan(p1[1]), qnan(p1[2]), qnan(p1[3]));
        if (q < 2)
            *(float4*)(orow + 32 + 4 * q) =
                make_float4(qnan(p2[0]), qnan(p2[1]), qnan(p2[2]), qnan(p2[3]));
    }
}

extern "C" void kernel_launch(void* const* d_in, const int* in_sizes, int n_in,
                              void* d_out, int out_size, void* d_ws, size_t ws_size,
                              hipStream_t stream) {
    const int*   x      = (const int*)  d_in[0];
    const float* hidden = (const float*)d_in[1];
    const float* emb    = (const float*)d_in[2];
    const float* Wh     = (const float*)d_in[3];
    const float* Wo     = (const float*)d_in[4];
    const float* bh     = (const float*)d_in[5];
    const float* by     = (const float*)d_in[6];
    float*       out    = (float*)      d_out;
    __bf16*      Hws    = (__bf16*)     d_ws;   // needs B*L*H*2 = 64 MB

    rnn_recur<<<dim3(BB / MB), dim3(256), 0, stream>>>(x, hidden, emb, Wh, bh, out, Hws);
    logits_gemm<<<dim3(BB * LL / 256), dim3(256), 0, stream>>>(Hws, Wo, by, out);
}

// Round 13
// 464.626 us; speedup vs baseline: 1.4025x; 1.1997x over previous
//
#include <hip/hip_runtime.h>

// CharRNN fused, MFMA v6: TWO-PHASE, bf16-LDS recurrence.  B=256,L=1024,V=40,H=128.
//
// R15 post-mortem: rnn_recur 455us = 1066 cyc/step; active-CU VALUBusy ~42%
// => ~450 cyc/step of VALU issue on the serial chain. Census: biggest block
// is the per-step fp32->bf16 B-fragment conversion (~48 instrs) because h
// lives in LDS as fp32. R11's NaN is exonerated (R12 fp32-LDS still NaN'd,
// R14 amputation fixed it) -> bf16-in-LDS is safe. R16:
//   1. h stored in LDS as bf16 (pitch 136): B-frags = 4 direct ds_read_b128,
//      ZERO per-step conversion; one tanh->bf16 cast (8 vals) feeds both LDS
//      and Hws. clamp1 dropped (recurrence proven NaN-free; phase-2 qnan
//      bands keep failures finite). Hws pointer strength-reduced; final-
//      hidden store moved out of the loop.
//   2. Phase 2: preload ALL 16 B-fragments before any MFMA (loads were
//      latency-serialized at ~1 TB/s effective).
//
// Structure (R14/R15, verified): phase 1 rnn_recur, 16 blocks x 256 (4 waves),
// D[j x m] = Wh . h^T per step, raw lgkmcnt+s_barrier (global ops drain
// lazily). Phase 2 logits_gemm, 1024 blocks x 256: out = H.Wo^T + b_y.
// MFMA 16x16x32 bf16 maps (m89): lane l=(q=l>>4, n=l&15):
//   A: row=n, k=q*8+e | B: col=n, k=q*8+e | D: col=n, row=4q+r

#define BB 256
#define LL 1024
#define VV 40
#define HH 128
#define MB 16           // batch per block (phase 1)
#define EP 132          // emb_s row pitch (floats)
#define HP2 136         // h LDS row pitch (bf16 elems; 272B rows, 16B-aligned)

typedef __bf16 bf16x8 __attribute__((ext_vector_type(8)));
typedef __bf16 bf16x4 __attribute__((ext_vector_type(4)));
typedef float  f32x4  __attribute__((ext_vector_type(4)));

#define MFMA(a, b, c) __builtin_amdgcn_mfma_f32_16x16x32_bf16((a), (b), (c), 0, 0, 0)

__device__ __forceinline__ float fast_tanh(float x) {
    // tanh(x) = 1 - 2/(exp(2x)+1); overflow -> inf -> rcp -> 0 -> +1 (correct)
    float e = __expf(2.0f * x);
    float r = __builtin_amdgcn_rcpf(e + 1.0f);
    return 1.0f - 2.0f * r;
}

__device__ __forceinline__ float qnan(float x) {     // NaN/huge -> +-1e30
    return fminf(1.0e30f, fmaxf(-1.0e30f, x));
}

// ============================ PHASE 1 ====================================
__global__ __launch_bounds__(256) void rnn_recur(
    const int*   __restrict__ x,       // [B,L]
    const float* __restrict__ hidden,  // [B,H]
    const float* __restrict__ emb,     // [V,H]
    const float* __restrict__ Wh,      // [H,H]
    const float* __restrict__ b_h,     // [H]
    float*       __restrict__ out,     // final hidden -> out[B*L*V ..]
    __bf16*      __restrict__ Hws)     // [B,L,H] bf16 workspace
{
    __shared__ float  emb_s[VV * EP];                  // 20.6 KB, b_h folded
    __shared__ __align__(16) __bf16 h2[2][MB][HP2];    //  8.5 KB, bf16 dbuf

    const int tid  = threadIdx.x;
    const int w    = tid >> 6;          // wave 0..3
    const int lane = tid & 63;
    const int m    = lane & 15;         // batch column (B col, D col)
    const int q    = lane >> 4;         // 0..3
    const int b0   = blockIdx.x * MB;

    for (int i = tid; i < VV * HH; i += 256) {
        int v = i >> 7, j = i & (HH - 1);
        emb_s[v * EP + j] = emb[i] + b_h[j];
    }
    for (int i = tid; i < MB * HH; i += 256) {
        int mm = i >> 7, j = i & (HH - 1);
        h2[0][mm][j] = (__bf16)hidden[(size_t)(b0 + mm) * HH + j];
    }

    // static A-fragments: Wh, 2 M-tiles/wave (rows j=(2w+i)*16+m)
    bf16x8 whA[2][4];
    #pragma unroll
    for (int i = 0; i < 2; ++i) {
        int j = (2 * w + i) * 16 + m;
        #pragma unroll
        for (int kt = 0; kt < 4; ++kt) {
            const float* pw = Wh + (size_t)j * HH + kt * 32 + q * 8;
            bf16x8 f;
            #pragma unroll
            for (int e = 0; e < 8; ++e) f[e] = (__bf16)pw[e];
            whA[i][kt] = f;
        }
    }

    const int* xrow = x + (size_t)(b0 + m) * LL;
    const int j00 = 32 * w + 4 * q;          // D row-quad base, M-tile 0
    const int j01 = j00 + 16;                // D row-quad base, M-tile 1
    int xl_nxt = xrow[1];
    __syncthreads();                         // staging complete (full barrier ok)

    f32x4 e0, e1;
    {
        int idx0 = xrow[0];
        e0 = *(const f32x4*)&emb_s[idx0 * EP + j00];
        e1 = *(const f32x4*)&emb_s[idx0 * EP + j01];
    }

    __bf16* hw = Hws + (((size_t)(b0 + m) * LL) << 7);  // row t=0; += HH per step
    int p = 0;
    f32x4 h0, h1;                            // last step's h stays for epilogue

    for (int t = 0; t < LL; ++t) {
        // ---- B-fragments: 4 direct ds_read_b128, zero conversion ----
        const __bf16* hb = h2[p][m];
        bf16x8 B0 = *(const bf16x8*)&hb[      q * 8];
        bf16x8 B1 = *(const bf16x8*)&hb[32 +  q * 8];
        bf16x8 B2 = *(const bf16x8*)&hb[64 +  q * 8];
        bf16x8 B3 = *(const bf16x8*)&hb[96 +  q * 8];

        int tn  = (t + 2 < LL) ? t + 2 : LL - 1;
        int xl2 = xrow[tn];                  // global; drains lazily

        // ---- main MFMAs: pre-activation, C initialized with e_t ----
        f32x4 c0 = e0, c1 = e1;
        c0 = MFMA(whA[0][0], B0, c0); c0 = MFMA(whA[0][1], B1, c0);
        c0 = MFMA(whA[0][2], B2, c0); c0 = MFMA(whA[0][3], B3, c0);
        c1 = MFMA(whA[1][0], B0, c1); c1 = MFMA(whA[1][1], B1, c1);
        c1 = MFMA(whA[1][2], B2, c1); c1 = MFMA(whA[1][3], B3, c1);

        // ---- e for t+1 (emb_s read-only; xl_nxt from last iter's load) ----
        e0 = *(const f32x4*)&emb_s[xl_nxt * EP + j00];
        e1 = *(const f32x4*)&emb_s[xl_nxt * EP + j01];
        xl_nxt = xl2;

        // ---- tanh, single bf16 cast feeds LDS dbuf AND Hws ----
        #pragma unroll
        for (int r = 0; r < 4; ++r) {
            h0[r] = fast_tanh(c0[r]);
            h1[r] = fast_tanh(c1[r]);
        }
        bf16x4 g0, g1;
        #pragma unroll
        for (int r = 0; r < 4; ++r) { g0[r] = (__bf16)h0[r]; g1[r] = (__bf16)h1[r]; }
        *(bf16x4*)&h2[p ^ 1][m][j00] = g0;
        *(bf16x4*)&h2[p ^ 1][m][j01] = g1;
        *(bf16x4*)&hw[j00] = g0;             // global stores stay in flight
        *(bf16x4*)&hw[j01] = g1;
        hw += HH;

        // ---- RAW barrier: LDS-only drain; global ops NOT drained ----
        asm volatile("s_waitcnt lgkmcnt(0)" ::: "memory");
        __builtin_amdgcn_s_barrier();
        __builtin_amdgcn_sched_barrier(0);   // rule #18: pin post-barrier reads
        p ^= 1;
    }

    // ---- final hidden (Output 1), fp32 from registers ----
    float* fh = out + (size_t)BB * LL * VV + (size_t)(b0 + m) * HH;
    *(float4*)(fh + j00) = make_float4(h0[0], h0[1], h0[2], h0[3]);
    *(float4*)(fh + j01) = make_float4(h1[0], h1[1], h1[2], h1[3]);
}

// ============================ PHASE 2 ====================================
// out[r][v] = sum_k H[r][k] * Wo[v][k] + b_y[v],  r = b*L+t in [0, B*L).
// Block: 256 rows (4 waves x 64). Wave: 4 groups of 16 rows.
// All 16 B-fragment loads issued BEFORE any MFMA (batch the HBM latency).
__global__ __launch_bounds__(256) void logits_gemm(
    const __bf16* __restrict__ Hws,    // [B*L, H] bf16
    const float*  __restrict__ Wo,     // [V,H]
    const float*  __restrict__ b_y,    // [V]
    float*        __restrict__ out)    // [B*L, V]
{
    const int tid  = threadIdx.x;
    const int w    = tid >> 6;
    const int lane = tid & 63;
    const int n    = lane & 15;         // col within 16-row group
    const int q    = lane >> 4;
    const int rbase = blockIdx.x * 256 + w * 64;

    // A-fragments: Wo v-tiles (rows v = vt*16+n; zero past VV)
    bf16x8 woA[3][4];
    f32x4  pInit[3];
    #pragma unroll
    for (int vt = 0; vt < 3; ++vt) {
        int vrow = vt * 16 + n;
        #pragma unroll
        for (int kt = 0; kt < 4; ++kt) {
            bf16x8 f;
            #pragma unroll
            for (int e = 0; e < 8; ++e) {
                float fv = 0.f;
                if (vrow < VV) fv = Wo[(size_t)vrow * HH + kt * 32 + q * 8 + e];
                f[e] = (__bf16)fv;
            }
            woA[vt][kt] = f;
        }
        #pragma unroll
        for (int r = 0; r < 4; ++r) {
            int v = vt * 16 + 4 * q + r;
            pInit[vt][r] = (v < VV) ? b_y[v] : 0.f;
        }
    }

    // ---- preload all 16 B-fragments (4 rows x 4 k-frags) ----
    bf16x8 Bf[4][4];
    #pragma unroll
    for (int g = 0; g < 4; ++g) {
        const __bf16* rp = Hws + (((size_t)rbase + g * 16 + n) << 7);
        Bf[g][0] = *(const bf16x8*)&rp[ 0 + q * 8];
        Bf[g][1] = *(const bf16x8*)&rp[32 + q * 8];
        Bf[g][2] = *(const bf16x8*)&rp[64 + q * 8];
        Bf[g][3] = *(const bf16x8*)&rp[96 + q * 8];
    }

    #pragma unroll
    for (int g = 0; g < 4; ++g) {
        const size_t row = (size_t)rbase + g * 16 + n;
        f32x4 p0 = pInit[0], p1 = pInit[1], p2 = pInit[2];
        p0 = MFMA(woA[0][0], Bf[g][0], p0); p0 = MFMA(woA[0][1], Bf[g][1], p0);
        p0 = MFMA(woA[0][2], Bf[g][2], p0); p0 = MFMA(woA[0][3], Bf[g][3], p0);
        p1 = MFMA(woA[1][0], Bf[g][0], p1); p1 = MFMA(woA[1][1], Bf[g][1], p1);
        p1 = MFMA(woA[1][2], Bf[g][2], p1); p1 = MFMA(woA[1][3], Bf[g][3], p1);
        p2 = MFMA(woA[2][0], Bf[g][0], p2); p2 = MFMA(woA[2][1], Bf[g][1], p2);
        p2 = MFMA(woA[2][2], Bf[g][2], p2); p2 = MFMA(woA[2][3], Bf[g][3], p2);

        // stores: lane holds D[v = vt*16+4q+r][row]; v-quads contiguous
        float* orow = out + row * VV;
        *(float4*)(orow + 4 * q) =
            make_float4(qnan(p0[0]), qnan(p0[1]), qnan(p0[2]), qnan(p0[3]));
        *(float4*)(orow + 16 + 4 * q) =
            make_float4(qnan(p1[0]), qnan(p1[1]), qnan(p1[2]), qnan(p1[3]));
        if (q < 2)
            *(float4*)(orow + 32 + 4 * q) =
                make_float4(qnan(p2[0]), qnan(p2[1]), qnan(p2[2]), qnan(p2[3]));
    }
}

extern "C" void kernel_launch(void* const* d_in, const int* in_sizes, int n_in,
                              void* d_out, int out_size, void* d_ws, size_t ws_size,
                              hipStream_t stream) {
    const int*   x      = (const int*)  d_in[0];
    const float* hidden = (const float*)d_in[1];
    const float* emb    = (const float*)d_in[2];
    const float* Wh     = (const float*)d_in[3];
    const float* Wo     = (const float*)d_in[4];
    const float* bh     = (const float*)d_in[5];
    const float* by     = (const float*)d_in[6];
    float*       out    = (float*)      d_out;
    __bf16*      Hws    = (__bf16*)     d_ws;   // needs B*L*H*2 = 64 MB

    rnn_recur<<<dim3(BB / MB), dim3(256), 0, stream>>>(x, hidden, emb, Wh, bh, out, Hws);
    logits_gemm<<<dim3(BB * LL / 256), dim3(256), 0, stream>>>(Hws, Wo, by, out);
}